// Round 1
// baseline (461.711 us; speedup 1.0000x reference)
//
#include <hip/hip_runtime.h>

typedef unsigned short u16;
typedef __bf16 bf16x8 __attribute__((ext_vector_type(8)));
typedef float f32x4 __attribute__((ext_vector_type(4)));

__device__ __forceinline__ u16 f2bf(float f){
  union{float f; unsigned u;} v; v.f = f;
  return (u16)((v.u + 0x7fffu + ((v.u >> 16) & 1u)) >> 16);
}

// ---------------------------------------------------------------------------
// transpose + cast fp32 [R][C] -> bf16 [C][R]
__global__ void tpose_cast(u16* __restrict__ dst, const float* __restrict__ src, int R, int C){
  __shared__ float t[32][33];
  int c0 = blockIdx.x * 32, r0 = blockIdx.y * 32;
  int tx = threadIdx.x, ty = threadIdx.y;
  #pragma unroll
  for (int i = 0; i < 4; i++)
    t[ty + i*8][tx] = src[(size_t)(r0 + ty + i*8) * C + c0 + tx];
  __syncthreads();
  #pragma unroll
  for (int i = 0; i < 4; i++)
    dst[(size_t)(c0 + ty + i*8) * R + r0 + tx] = f2bf(t[tx][ty + i*8]);
}

// bias_sum = spatial + edge  (float4)
__global__ void add2_kernel(float* __restrict__ dst, const float* __restrict__ a,
                            const float* __restrict__ b){
  int i = blockIdx.x * blockDim.x + threadIdx.x;
  float4 va = ((const float4*)a)[i], vb = ((const float4*)b)[i];
  float4 r{va.x+vb.x, va.y+vb.y, va.z+vb.z, va.w+vb.w};
  ((float4*)dst)[i] = r;
}

// qkvb[0:1536)=0, qkvb[1536+i]=bv[i]
__global__ void build_qkvb(float* __restrict__ qkvb, const float* __restrict__ bv){
  int i = blockIdx.x * blockDim.x + threadIdx.x;
  if (i < 2304) qkvb[i] = (i < 1536) ? 0.f : bv[i - 1536];
}

// ---------------------------------------------------------------------------
// LayerNorm: one wave per row, produce h1 (g1,be1) and h2 (g2,be2) in bf16
__global__ __launch_bounds__(256) void ln_kernel(
    const float* __restrict__ x,
    const float* __restrict__ g1, const float* __restrict__ be1,
    const float* __restrict__ g2, const float* __restrict__ be2,
    u16* __restrict__ h1, u16* __restrict__ h2){
  const int lane = threadIdx.x & 63, wave = threadIdx.x >> 6;
  const int row = blockIdx.x * 4 + wave;
  const float4* xr = (const float4*)(x + (size_t)row * 768);
  float4 v[3];
  float sum = 0.f, sq = 0.f;
  #pragma unroll
  for (int c = 0; c < 3; c++){
    v[c] = xr[lane + 64*c];
    sum += v[c].x + v[c].y + v[c].z + v[c].w;
    sq  += v[c].x*v[c].x + v[c].y*v[c].y + v[c].z*v[c].z + v[c].w*v[c].w;
  }
  #pragma unroll
  for (int d = 1; d < 64; d <<= 1){ sum += __shfl_xor(sum, d); sq += __shfl_xor(sq, d); }
  float mu  = sum * (1.f/768.f);
  float var = sq * (1.f/768.f) - mu*mu;
  float rs  = rsqrtf(var + 1e-5f);
  #pragma unroll
  for (int c = 0; c < 3; c++){
    int f4 = lane + 64*c;
    float4 ga = ((const float4*)g1)[f4], ba = ((const float4*)be1)[f4];
    float4 gb = ((const float4*)g2)[f4], bb = ((const float4*)be2)[f4];
    float nx = (v[c].x-mu)*rs, ny = (v[c].y-mu)*rs, nz = (v[c].z-mu)*rs, nw = (v[c].w-mu)*rs;
    ushort4 o1{f2bf(nx*ga.x+ba.x), f2bf(ny*ga.y+ba.y), f2bf(nz*ga.z+ba.z), f2bf(nw*ga.w+ba.w)};
    ushort4 o2{f2bf(nx*gb.x+bb.x), f2bf(ny*gb.y+bb.y), f2bf(nz*gb.z+bb.z), f2bf(nw*gb.w+bb.w)};
    ((ushort4*)(h1 + (size_t)row*768))[f4] = o1;
    ((ushort4*)(h2 + (size_t)row*768))[f4] = o2;
  }
}

// ---------------------------------------------------------------------------
// GEMM: C[M,N] = A[M,K](bf16) @ Bt[N,K](bf16)^T, fp32 accum.
// EPI 0: +bias -> bf16     EPI 1: +bias +resid(f32) -> f32     EPI 2: +bias, gelu -> bf16
template<int EPI>
__global__ __launch_bounds__(256, 2) void gemm_bt(
    const u16* __restrict__ A, const u16* __restrict__ Bt, void* __restrict__ Cout,
    const float* __restrict__ bias, const float* __restrict__ resid,
    int M, int Nn, int K){
  __shared__ __align__(16) u16 As[128*40];
  __shared__ __align__(16) u16 Bs[128*40];
  const int tid = threadIdx.x, lane = tid & 63, wave = tid >> 6;
  const int wm = wave >> 1, wn = wave & 1;
  const int l15 = lane & 15, lg = lane >> 4;
  const int m0 = blockIdx.y * 128, n0 = blockIdx.x * 128;
  f32x4 acc[4][4] = {};
  for (int k0 = 0; k0 < K; k0 += 32){
    #pragma unroll
    for (int c = tid; c < 512; c += 256){
      int row = c >> 2, seg = c & 3;
      *(uint4*)&As[row*40 + seg*8] = *(const uint4*)&A [(size_t)(m0+row)*K + k0 + seg*8];
      *(uint4*)&Bs[row*40 + seg*8] = *(const uint4*)&Bt[(size_t)(n0+row)*K + k0 + seg*8];
    }
    __syncthreads();
    bf16x8 af[4], bf[4];
    #pragma unroll
    for (int i = 0; i < 4; i++){
      af[i] = *(const bf16x8*)&As[(wm*64 + i*16 + l15)*40 + lg*8];
      bf[i] = *(const bf16x8*)&Bs[(wn*64 + i*16 + l15)*40 + lg*8];
    }
    #pragma unroll
    for (int i = 0; i < 4; i++)
      #pragma unroll
      for (int j = 0; j < 4; j++)
        acc[i][j] = __builtin_amdgcn_mfma_f32_16x16x32_bf16(af[i], bf[j], acc[i][j], 0, 0, 0);
    __syncthreads();
  }
  #pragma unroll
  for (int i = 0; i < 4; i++){
    int row_base = m0 + wm*64 + i*16 + lg*4;
    #pragma unroll
    for (int j = 0; j < 4; j++){
      int col = n0 + wn*64 + j*16 + l15;
      float bb = bias ? bias[col] : 0.f;
      #pragma unroll
      for (int r = 0; r < 4; r++){
        size_t idx = (size_t)(row_base + r) * Nn + col;
        float v = acc[i][j][r] + bb;
        if (EPI == 1){
          v += resid[idx];
          ((float*)Cout)[idx] = v;
        } else if (EPI == 2){
          float t = tanhf(0.7978845608028654f * (v + 0.044715f*v*v*v));
          ((u16*)Cout)[idx] = f2bf(0.5f * v * (1.f + t));
        } else {
          ((u16*)Cout)[idx] = f2bf(v);
        }
      }
    }
  }
}

// ---------------------------------------------------------------------------
// qkv [8192][2304] bf16 -> Q [B,H,N,64], K [B,H,N,64] (coalesced 16B chunks)
__global__ void reshape_qk(const u16* __restrict__ qkv, u16* __restrict__ Qg, u16* __restrict__ Kg){
  int tid = blockIdx.x * blockDim.x + threadIdx.x;   // 8192*96
  int row = tid / 96, cc = tid % 96;
  int b = row >> 9, n = row & 511;
  int h = cc >> 3, hd0 = (cc & 7) * 8;
  size_t dst = ((size_t)(b*12 + h)*512 + n)*64 + hd0;
  *(uint4*)&Qg[dst] = *(const uint4*)&qkv[(size_t)row*2304 + cc*8];
  *(uint4*)&Kg[dst] = *(const uint4*)&qkv[(size_t)row*2304 + 768 + cc*8];
}

// qkv v-part -> VT [B,H,64,N] via LDS tile transpose
__global__ void vtrans(const u16* __restrict__ qkv, u16* __restrict__ VTg){
  __shared__ u16 t[32][33];
  int bh = blockIdx.z, b = bh / 12, h = bh % 12;
  int n0 = blockIdx.x * 32, hd0 = blockIdx.y * 32;
  int tx = threadIdx.x, ty = threadIdx.y;
  #pragma unroll
  for (int i = 0; i < 4; i++){
    int n = n0 + ty + i*8;
    t[ty + i*8][tx] = qkv[((size_t)(b*512 + n))*2304 + 1536 + h*64 + hd0 + tx];
  }
  __syncthreads();
  #pragma unroll
  for (int i = 0; i < 4; i++){
    int hd = hd0 + ty + i*8;
    VTg[((size_t)bh*64 + hd)*512 + n0 + tx] = t[tx][ty + i*8];
  }
}

// ---------------------------------------------------------------------------
// Flash attention: block = (q-tile 128) x (b,h); 4 waves, each 32 q-rows.
__global__ __launch_bounds__(256, 2) void attn_kernel(
    const u16* __restrict__ Qg, const u16* __restrict__ Kg, const u16* __restrict__ VTg,
    const float* __restrict__ biasS, u16* __restrict__ Og){
  __shared__ __align__(16) u16 Pl[4*32*136];
  const int tid = threadIdx.x, lane = tid & 63, wave = tid >> 6;
  const int l15 = lane & 15, lg = lane >> 4;
  const int bh = blockIdx.y, b = bh / 12, h = bh % 12;
  const int q0 = blockIdx.x * 128 + wave * 32;
  const u16* Qbh = Qg + (size_t)bh * 512 * 64;
  const u16* Kbh = Kg + (size_t)bh * 512 * 64;
  const u16* Vbh = VTg + (size_t)bh * 64 * 512;
  const float* bias_b = biasS + (size_t)b * 512 * 512;
  u16* Pw = &Pl[wave * 32 * 136];
  const float scale = 0.03608439182435161f;  // 768^-0.5

  bf16x8 qf[2][2];
  #pragma unroll
  for (int fm = 0; fm < 2; fm++)
    #pragma unroll
    for (int kk = 0; kk < 2; kk++)
      qf[fm][kk] = *(const bf16x8*)&Qbh[(size_t)(q0 + fm*16 + l15)*64 + kk*32 + lg*8];

  f32x4 O[2][4] = {};
  float mrow[2][4], lrow[2][4];
  #pragma unroll
  for (int fm = 0; fm < 2; fm++)
    #pragma unroll
    for (int r = 0; r < 4; r++){ mrow[fm][r] = -1e30f; lrow[fm][r] = 0.f; }

  for (int kt = 0; kt < 4; kt++){
    const int k0 = kt * 128;
    f32x4 S[2][8] = {};
    #pragma unroll
    for (int fk = 0; fk < 8; fk++)
      #pragma unroll
      for (int kk = 0; kk < 2; kk++){
        bf16x8 kf = *(const bf16x8*)&Kbh[(size_t)(k0 + fk*16 + l15)*64 + kk*32 + lg*8];
        S[0][fk] = __builtin_amdgcn_mfma_f32_16x16x32_bf16(qf[0][kk], kf, S[0][fk], 0,0,0);
        S[1][fk] = __builtin_amdgcn_mfma_f32_16x16x32_bf16(qf[1][kk], kf, S[1][fk], 0,0,0);
      }
    // scale + bias + online softmax (row r of lane = q0+fm*16+lg*4+r, col = k0+fk*16+l15)
    #pragma unroll
    for (int fm = 0; fm < 2; fm++)
      #pragma unroll
      for (int r = 0; r < 4; r++){
        int qrow = q0 + fm*16 + lg*4 + r;
        const float* bp = bias_b + (size_t)qrow*512 + k0 + l15;
        float mx = -1e30f;
        #pragma unroll
        for (int fk = 0; fk < 8; fk++){
          float s = S[fm][fk][r] * scale + bp[fk*16];
          S[fm][fk][r] = s;
          mx = fmaxf(mx, s);
        }
        mx = fmaxf(mx, __shfl_xor(mx, 1));
        mx = fmaxf(mx, __shfl_xor(mx, 2));
        mx = fmaxf(mx, __shfl_xor(mx, 4));
        mx = fmaxf(mx, __shfl_xor(mx, 8));
        float mnew = fmaxf(mrow[fm][r], mx);
        float fac = __expf(mrow[fm][r] - mnew);
        mrow[fm][r] = mnew;
        float rs = 0.f;
        #pragma unroll
        for (int fk = 0; fk < 8; fk++){
          float p = __expf(S[fm][fk][r] - mnew);
          S[fm][fk][r] = p;
          rs += p;
        }
        rs += __shfl_xor(rs, 1); rs += __shfl_xor(rs, 2);
        rs += __shfl_xor(rs, 4); rs += __shfl_xor(rs, 8);
        lrow[fm][r] = lrow[fm][r] * fac + rs;
        #pragma unroll
        for (int fn = 0; fn < 4; fn++) O[fm][fn][r] *= fac;
      }
    __syncthreads();   // previous iteration's P reads are done before overwrite
    #pragma unroll
    for (int fm = 0; fm < 2; fm++)
      #pragma unroll
      for (int fk = 0; fk < 8; fk++)
        #pragma unroll
        for (int r = 0; r < 4; r++)
          Pw[(fm*16 + lg*4 + r)*136 + fk*16 + l15] = f2bf(S[fm][fk][r]);
    __syncthreads();
    bf16x8 pf[2][4];
    #pragma unroll
    for (int fm = 0; fm < 2; fm++)
      #pragma unroll
      for (int kk = 0; kk < 4; kk++)
        pf[fm][kk] = *(const bf16x8*)&Pw[(fm*16 + l15)*136 + kk*32 + lg*8];
    #pragma unroll
    for (int fn = 0; fn < 4; fn++)
      #pragma unroll
      for (int kk = 0; kk < 4; kk++){
        bf16x8 vf = *(const bf16x8*)&Vbh[(size_t)(fn*16 + l15)*512 + k0 + kk*32 + lg*8];
        O[0][fn] = __builtin_amdgcn_mfma_f32_16x16x32_bf16(pf[0][kk], vf, O[0][fn], 0,0,0);
        O[1][fn] = __builtin_amdgcn_mfma_f32_16x16x32_bf16(pf[1][kk], vf, O[1][fn], 0,0,0);
      }
  }
  #pragma unroll
  for (int fm = 0; fm < 2; fm++)
    #pragma unroll
    for (int fn = 0; fn < 4; fn++)
      #pragma unroll
      for (int r = 0; r < 4; r++){
        int qrow = q0 + fm*16 + lg*4 + r;
        float v = O[fm][fn][r] / lrow[fm][r];
        Og[((size_t)b*512 + qrow)*768 + h*64 + fn*16 + l15] = f2bf(v);
      }
}

// ---------------------------------------------------------------------------
extern "C" void kernel_launch(void* const* d_in, const int* in_sizes, int n_in,
                              void* d_out, int out_size, void* d_ws, size_t ws_size,
                              hipStream_t stream){
  const float* x   = (const float*)d_in[0];
  const float* sp  = (const float*)d_in[1];
  const float* ed  = (const float*)d_in[2];
  const float* Wq  = (const float*)d_in[3];
  const float* Wk  = (const float*)d_in[4];
  const float* Wv  = (const float*)d_in[5];
  const float* bv  = (const float*)d_in[6];
  const float* Wo  = (const float*)d_in[7];
  const float* bo  = (const float*)d_in[8];
  const float* g1  = (const float*)d_in[9];
  const float* be1 = (const float*)d_in[10];
  const float* g2  = (const float*)d_in[11];
  const float* be2 = (const float*)d_in[12];
  const float* W1  = (const float*)d_in[13];
  const float* bf1 = (const float*)d_in[14];
  const float* W2  = (const float*)d_in[15];
  const float* bf2 = (const float*)d_in[16];

  char* w = (char*)d_ws;
  size_t off = 0;
  auto alloc = [&](size_t bytes)->void*{ void* p = w + off; off += (bytes + 255) & ~(size_t)255; return p; };
  u16*   qkv   = (u16*)  alloc(8192ull*2304*2);   // 37,748,736
  u16*   Qg    = (u16*)  alloc(8192ull*768*2);    // 12,582,912
  u16*   Kg    = (u16*)  alloc(8192ull*768*2);
  u16*   VTg   = (u16*)  alloc(8192ull*768*2);
  u16*   h1    = (u16*)  alloc(8192ull*768*2);
  u16*   h2    = (u16*)  alloc(8192ull*768*2);
  u16*   Og    = (u16*)  alloc(8192ull*768*2);
  float* att   = (float*)alloc(8192ull*768*4);    // 25,165,824
  float* biasS = (float*)alloc(16ull*512*512*4);  // 16,777,216
  u16*   WqkvT = (u16*)  alloc(2304ull*768*2);
  u16*   WoT   = (u16*)  alloc(768ull*768*2);
  u16*   W1T   = (u16*)  alloc(3072ull*768*2);
  u16*   W2T   = (u16*)  alloc(768ull*3072*2);
  float* qkvb  = (float*)alloc(2304ull*4);
  u16*   Gg    = qkv;  // G [8192][3072] bf16 overlays qkv+Qg (both dead by FFN1)

  // --- prep ---
  tpose_cast<<<dim3(24,24),dim3(32,8),0,stream>>>(WqkvT,            Wq, 768, 768);
  tpose_cast<<<dim3(24,24),dim3(32,8),0,stream>>>(WqkvT + 768*768,  Wk, 768, 768);
  tpose_cast<<<dim3(24,24),dim3(32,8),0,stream>>>(WqkvT + 1536*768, Wv, 768, 768);
  tpose_cast<<<dim3(24,24),dim3(32,8),0,stream>>>(WoT,              Wo, 768, 768);
  tpose_cast<<<dim3(96,24),dim3(32,8),0,stream>>>(W1T, W1, 768, 3072);
  tpose_cast<<<dim3(24,96),dim3(32,8),0,stream>>>(W2T, W2, 3072, 768);
  add2_kernel<<<4096,256,0,stream>>>(biasS, sp, ed);
  build_qkvb<<<9,256,0,stream>>>(qkvb, bv);

  // --- layer norms (shared stats) ---
  ln_kernel<<<2048,256,0,stream>>>(x, g1, be1, g2, be2, h1, h2);

  // --- qkv projection ---
  gemm_bt<0><<<dim3(18,64),256,0,stream>>>(h1, WqkvT, qkv, qkvb, nullptr, 8192, 2304, 768);
  reshape_qk<<<3072,256,0,stream>>>(qkv, Qg, Kg);
  vtrans<<<dim3(16,2,192),dim3(32,8),0,stream>>>(qkv, VTg);

  // --- attention ---
  attn_kernel<<<dim3(4,192),256,0,stream>>>(Qg, Kg, VTg, biasS, Og);

  // --- output projection + residual x ---
  gemm_bt<1><<<dim3(6,64),256,0,stream>>>(Og, WoT, att, bo, x, 8192, 768, 768);

  // --- FFN ---
  gemm_bt<2><<<dim3(24,64),256,0,stream>>>(h2, W1T, Gg, bf1, nullptr, 8192, 3072, 768);
  gemm_bt<1><<<dim3(6,64),256,0,stream>>>(Gg, W2T, (float*)d_out, bf2, att, 8192, 768, 3072);
}

// Round 2
// 351.531 us; speedup vs baseline: 1.3134x; 1.3134x over previous
//
#include <hip/hip_runtime.h>
#include <math.h>

typedef unsigned short u16;
typedef __bf16 bf16x8 __attribute__((ext_vector_type(8)));
typedef float f32x4 __attribute__((ext_vector_type(4)));

__device__ __forceinline__ u16 f2bf(float f){
  union{float f; unsigned u;} v; v.f = f;
  return (u16)((v.u + 0x7fffu + ((v.u >> 16) & 1u)) >> 16);
}

#define LOG2E 1.4426950408889634f

// ---------------------------------------------------------------------------
// transpose + cast + scale: fp32 [R][C] -> bf16 [C][R] * scale
__global__ void tpose_cast(u16* __restrict__ dst, const float* __restrict__ src,
                           int R, int C, float scale){
  __shared__ float t[32][33];
  int c0 = blockIdx.x * 32, r0 = blockIdx.y * 32;
  int tx = threadIdx.x, ty = threadIdx.y;
  #pragma unroll
  for (int i = 0; i < 4; i++)
    t[ty + i*8][tx] = src[(size_t)(r0 + ty + i*8) * C + c0 + tx];
  __syncthreads();
  #pragma unroll
  for (int i = 0; i < 4; i++)
    dst[(size_t)(c0 + ty + i*8) * R + r0 + tx] = f2bf(t[tx][ty + i*8] * scale);
}

// biasP[b][q][kt][l15][fk] = (sp+ed)[b][q][kt*128 + fk*16 + l15] * log2e - 8*log2e
__global__ void bias_prep(float* __restrict__ dst, const float* __restrict__ sp,
                          const float* __restrict__ ed){
  int t = blockIdx.x * blockDim.x + threadIdx.x;   // 16*512*128
  int row = t >> 7, c0 = (t & 127) * 4;
  size_t base = (size_t)row * 512;
  float4 s = *(const float4*)&sp[base + c0];
  float4 e = *(const float4*)&ed[base + c0];
  const float SH = 8.f * LOG2E;
  int kt = c0 >> 7, cw = c0 & 127, fk = cw >> 4, l0 = cw & 15;
  float* o = dst + base + kt*128 + fk;
  o[(l0+0)*8] = (s.x+e.x)*LOG2E - SH;
  o[(l0+1)*8] = (s.y+e.y)*LOG2E - SH;
  o[(l0+2)*8] = (s.z+e.z)*LOG2E - SH;
  o[(l0+3)*8] = (s.w+e.w)*LOG2E - SH;
}

// qkvb[0:1536)=0, qkvb[1536+i]=bv[i]
__global__ void build_qkvb(float* __restrict__ qkvb, const float* __restrict__ bv){
  int i = blockIdx.x * blockDim.x + threadIdx.x;
  if (i < 2304) qkvb[i] = (i < 1536) ? 0.f : bv[i - 1536];
}

// ---------------------------------------------------------------------------
// LayerNorm: one wave per row, produce h1 (g1,be1) and h2 (g2,be2) in bf16
__global__ __launch_bounds__(256) void ln_kernel(
    const float* __restrict__ x,
    const float* __restrict__ g1, const float* __restrict__ be1,
    const float* __restrict__ g2, const float* __restrict__ be2,
    u16* __restrict__ h1, u16* __restrict__ h2){
  const int lane = threadIdx.x & 63, wave = threadIdx.x >> 6;
  const int row = blockIdx.x * 4 + wave;
  const float4* xr = (const float4*)(x + (size_t)row * 768);
  float4 v[3];
  float sum = 0.f, sq = 0.f;
  #pragma unroll
  for (int c = 0; c < 3; c++){
    v[c] = xr[lane + 64*c];
    sum += v[c].x + v[c].y + v[c].z + v[c].w;
    sq  += v[c].x*v[c].x + v[c].y*v[c].y + v[c].z*v[c].z + v[c].w*v[c].w;
  }
  #pragma unroll
  for (int d = 1; d < 64; d <<= 1){ sum += __shfl_xor(sum, d); sq += __shfl_xor(sq, d); }
  float mu  = sum * (1.f/768.f);
  float var = sq * (1.f/768.f) - mu*mu;
  float rs  = rsqrtf(var + 1e-5f);
  #pragma unroll
  for (int c = 0; c < 3; c++){
    int f4 = lane + 64*c;
    float4 ga = ((const float4*)g1)[f4], ba = ((const float4*)be1)[f4];
    float4 gb = ((const float4*)g2)[f4], bb = ((const float4*)be2)[f4];
    float nx = (v[c].x-mu)*rs, ny = (v[c].y-mu)*rs, nz = (v[c].z-mu)*rs, nw = (v[c].w-mu)*rs;
    ushort4 o1{f2bf(nx*ga.x+ba.x), f2bf(ny*ga.y+ba.y), f2bf(nz*ga.z+ba.z), f2bf(nw*ga.w+ba.w)};
    ushort4 o2{f2bf(nx*gb.x+bb.x), f2bf(ny*gb.y+bb.y), f2bf(nz*gb.z+bb.z), f2bf(nw*gb.w+bb.w)};
    ((ushort4*)(h1 + (size_t)row*768))[f4] = o1;
    ((ushort4*)(h2 + (size_t)row*768))[f4] = o2;
  }
}

// ---------------------------------------------------------------------------
// GEMM (m97 structure): C[M,N] = A[M,K](bf16) @ Bt[N,K](bf16)^T, fp32 accum.
// global_load_lds width=16 into linear [128][32] LDS tiles.
// EPI 0: +bias -> bf16   EPI 1: +bias +resid(f32) -> f32   EPI 2: +bias, gelu -> bf16
template<int EPI>
__global__ __launch_bounds__(256, 2) void gemm_bt(
    const u16* __restrict__ A, const u16* __restrict__ Bt, void* __restrict__ Cout,
    const float* __restrict__ bias, const float* __restrict__ resid,
    int M, int Nn, int K){
  __shared__ __align__(16) u16 As[128*32];
  __shared__ __align__(16) u16 Bs[128*32];
  const int tid = threadIdx.x, lane = tid & 63, wave = tid >> 6;
  const int wm = wave >> 1, wn = wave & 1;
  const int l15 = lane & 15, lg = lane >> 4;
  const int m0 = blockIdx.y * 128, n0 = blockIdx.x * 128;
  f32x4 acc[4][4] = {};
  for (int k0 = 0; k0 < K; k0 += 32){
    #pragma unroll
    for (int i = 0; i < 2; i++){
      int chunk = i*256 + tid;           // 16B chunk index, 512 per tile
      int row = chunk >> 2, seg = chunk & 3;
      __builtin_amdgcn_global_load_lds(
        (const __attribute__((address_space(1))) void*)&A[(size_t)(m0+row)*K + k0 + seg*8],
        (__attribute__((address_space(3))) void*)&As[(size_t)(i*256 + wave*64)*8],
        16, 0, 0);
      __builtin_amdgcn_global_load_lds(
        (const __attribute__((address_space(1))) void*)&Bt[(size_t)(n0+row)*K + k0 + seg*8],
        (__attribute__((address_space(3))) void*)&Bs[(size_t)(i*256 + wave*64)*8],
        16, 0, 0);
    }
    __syncthreads();
    bf16x8 af[4], bfr[4];
    #pragma unroll
    for (int i = 0; i < 4; i++){
      af[i]  = *(const bf16x8*)&As[(wm*64 + i*16 + l15)*32 + lg*8];
      bfr[i] = *(const bf16x8*)&Bs[(wn*64 + i*16 + l15)*32 + lg*8];
    }
    #pragma unroll
    for (int i = 0; i < 4; i++)
      #pragma unroll
      for (int j = 0; j < 4; j++)
        acc[i][j] = __builtin_amdgcn_mfma_f32_16x16x32_bf16(af[i], bfr[j], acc[i][j], 0, 0, 0);
    __syncthreads();
  }
  #pragma unroll
  for (int i = 0; i < 4; i++){
    int row_base = m0 + wm*64 + i*16 + lg*4;
    #pragma unroll
    for (int j = 0; j < 4; j++){
      int col = n0 + wn*64 + j*16 + l15;
      float bb = bias ? bias[col] : 0.f;
      #pragma unroll
      for (int r = 0; r < 4; r++){
        size_t idx = (size_t)(row_base + r) * Nn + col;
        float v = acc[i][j][r] + bb;
        if (EPI == 1){
          v += resid[idx];
          ((float*)Cout)[idx] = v;
        } else if (EPI == 2){
          // gelu_tanh(v) = v * sigmoid(1.5957691*(v + 0.044715 v^3))
          float u = v + 0.044715f * v * v * v;
          float e = exp2f(-2.3022182f * u);          // exp(-1.5957691*u)
          ((u16*)Cout)[idx] = f2bf(v * __builtin_amdgcn_rcpf(1.f + e));
        } else {
          ((u16*)Cout)[idx] = f2bf(v);
        }
      }
    }
  }
}

// ---------------------------------------------------------------------------
// qkv v-part -> VT [B,H,64,N] via LDS tile transpose
__global__ void vtrans(const u16* __restrict__ qkv, u16* __restrict__ VTg){
  __shared__ u16 t[32][33];
  int bh = blockIdx.z, b = bh / 12, h = bh % 12;
  int n0 = blockIdx.x * 32, hd0 = blockIdx.y * 32;
  int tx = threadIdx.x, ty = threadIdx.y;
  #pragma unroll
  for (int i = 0; i < 4; i++){
    int n = n0 + ty + i*8;
    t[ty + i*8][tx] = qkv[((size_t)(b*512 + n))*2304 + 1536 + h*64 + hd0 + tx];
  }
  __syncthreads();
  #pragma unroll
  for (int i = 0; i < 4; i++){
    int hd = hd0 + ty + i*8;
    VTg[((size_t)bh*64 + hd)*512 + n0 + tx] = t[tx][ty + i*8];
  }
}

// ---------------------------------------------------------------------------
// Attention: block = (q-tile 128) x (b,h); 4 independent waves, each 32 q-rows.
// Fixed-shift softmax (no online max), scale*log2e folded into Wq,
// (bias*log2e - 8*log2e) pre-permuted in biasP. No __syncthreads at all.
__global__ __launch_bounds__(256, 2) void attn_kernel(
    const u16* __restrict__ qkv, const u16* __restrict__ VTg,
    const float* __restrict__ biasP, u16* __restrict__ Og){
  __shared__ __align__(16) u16 Pl[4*32*136];
  const int tid = threadIdx.x, lane = tid & 63, wave = tid >> 6;
  const int l15 = lane & 15, lg = lane >> 4;
  const int bh = blockIdx.y, b = bh / 12, h = bh % 12;
  const int q0 = blockIdx.x * 128 + wave * 32;
  const u16* Qb = qkv + (size_t)b * 512 * 2304 + h * 64;   // row stride 2304
  const u16* Kb = Qb + 768;
  const u16* Vbh = VTg + (size_t)bh * 64 * 512;
  u16* Pw = &Pl[wave * 32 * 136];

  bf16x8 qf[2][2];
  #pragma unroll
  for (int fm = 0; fm < 2; fm++)
    #pragma unroll
    for (int kk = 0; kk < 2; kk++)
      qf[fm][kk] = *(const bf16x8*)&Qb[(size_t)(q0 + fm*16 + l15)*2304 + kk*32 + lg*8];

  f32x4 O[2][4] = {};
  float lrow[2][4] = {};

  for (int kt = 0; kt < 4; kt++){
    const int k0 = kt * 128;
    // bias: two f32x4 per (fm,r), pre-permuted layout
    f32x4 bb[2][4][2];
    #pragma unroll
    for (int fm = 0; fm < 2; fm++)
      #pragma unroll
      for (int r = 0; r < 4; r++){
        int qrow = q0 + fm*16 + lg*4 + r;
        const float* bp = biasP + ((size_t)(b*512 + qrow)*4 + kt)*128 + l15*8;
        bb[fm][r][0] = *(const f32x4*)bp;
        bb[fm][r][1] = *(const f32x4*)(bp + 4);
      }
    f32x4 S[2][8] = {};
    #pragma unroll
    for (int fk = 0; fk < 8; fk++)
      #pragma unroll
      for (int kk = 0; kk < 2; kk++){
        bf16x8 kf = *(const bf16x8*)&Kb[(size_t)(k0 + fk*16 + l15)*2304 + kk*32 + lg*8];
        S[0][fk] = __builtin_amdgcn_mfma_f32_16x16x32_bf16(qf[0][kk], kf, S[0][fk], 0,0,0);
        S[1][fk] = __builtin_amdgcn_mfma_f32_16x16x32_bf16(qf[1][kk], kf, S[1][fk], 0,0,0);
      }
    // p = exp2(qk*scale*log2e + bias*log2e - 8*log2e); row sums
    #pragma unroll
    for (int fm = 0; fm < 2; fm++)
      #pragma unroll
      for (int r = 0; r < 4; r++){
        float rs = 0.f;
        #pragma unroll
        for (int fk = 0; fk < 8; fk++){
          float p = exp2f(S[fm][fk][r] + bb[fm][r][fk>>2][fk&3]);
          S[fm][fk][r] = p;
          rs += p;
        }
        rs += __shfl_xor(rs, 1); rs += __shfl_xor(rs, 2);
        rs += __shfl_xor(rs, 4); rs += __shfl_xor(rs, 8);
        lrow[fm][r] += rs;
      }
    // P -> LDS (per-wave private; intra-wave lgkmcnt ordering, no barrier)
    #pragma unroll
    for (int fm = 0; fm < 2; fm++)
      #pragma unroll
      for (int fk = 0; fk < 8; fk++)
        #pragma unroll
        for (int r = 0; r < 4; r++)
          Pw[(fm*16 + lg*4 + r)*136 + fk*16 + l15] = f2bf(S[fm][fk][r]);
    bf16x8 pf[2][4];
    #pragma unroll
    for (int fm = 0; fm < 2; fm++)
      #pragma unroll
      for (int kk = 0; kk < 4; kk++)
        pf[fm][kk] = *(const bf16x8*)&Pw[(fm*16 + l15)*136 + kk*32 + lg*8];
    #pragma unroll
    for (int fn = 0; fn < 4; fn++)
      #pragma unroll
      for (int kk = 0; kk < 4; kk++){
        bf16x8 vf = *(const bf16x8*)&Vbh[(size_t)(fn*16 + l15)*512 + k0 + kk*32 + lg*8];
        O[0][fn] = __builtin_amdgcn_mfma_f32_16x16x32_bf16(pf[0][kk], vf, O[0][fn], 0,0,0);
        O[1][fn] = __builtin_amdgcn_mfma_f32_16x16x32_bf16(pf[1][kk], vf, O[1][fn], 0,0,0);
      }
  }
  #pragma unroll
  for (int fm = 0; fm < 2; fm++)
    #pragma unroll
    for (int r = 0; r < 4; r++){
      float inv = __builtin_amdgcn_rcpf(lrow[fm][r]);
      int qrow = q0 + fm*16 + lg*4 + r;
      #pragma unroll
      for (int fn = 0; fn < 4; fn++)
        Og[((size_t)b*512 + qrow)*768 + h*64 + fn*16 + l15] = f2bf(O[fm][fn][r] * inv);
    }
}

// ---------------------------------------------------------------------------
extern "C" void kernel_launch(void* const* d_in, const int* in_sizes, int n_in,
                              void* d_out, int out_size, void* d_ws, size_t ws_size,
                              hipStream_t stream){
  const float* x   = (const float*)d_in[0];
  const float* sp  = (const float*)d_in[1];
  const float* ed  = (const float*)d_in[2];
  const float* Wq  = (const float*)d_in[3];
  const float* Wk  = (const float*)d_in[4];
  const float* Wv  = (const float*)d_in[5];
  const float* bv  = (const float*)d_in[6];
  const float* Wo  = (const float*)d_in[7];
  const float* bo  = (const float*)d_in[8];
  const float* g1  = (const float*)d_in[9];
  const float* be1 = (const float*)d_in[10];
  const float* g2  = (const float*)d_in[11];
  const float* be2 = (const float*)d_in[12];
  const float* W1  = (const float*)d_in[13];
  const float* bf1 = (const float*)d_in[14];
  const float* W2  = (const float*)d_in[15];
  const float* bf2 = (const float*)d_in[16];

  char* w = (char*)d_ws;
  size_t off = 0;
  auto alloc = [&](size_t bytes)->void*{ void* p = w + off; off += (bytes + 255) & ~(size_t)255; return p; };
  u16*   Gg    = (u16*)  alloc(8192ull*3072*2);   // FFN1 out; first 37.7MB double as qkv
  u16*   qkv   = Gg;                               // [8192][2304] bf16 (dead before FFN1)
  u16*   VTg   = (u16*)  alloc(8192ull*768*2);
  u16*   h1    = (u16*)  alloc(8192ull*768*2);
  u16*   h2    = (u16*)  alloc(8192ull*768*2);
  u16*   Og    = (u16*)  alloc(8192ull*768*2);
  float* att   = (float*)alloc(8192ull*768*4);
  float* biasP = (float*)alloc(16ull*512*512*4);
  u16*   WqkvT = (u16*)  alloc(2304ull*768*2);
  u16*   WoT   = (u16*)  alloc(768ull*768*2);
  u16*   W1T   = (u16*)  alloc(3072ull*768*2);
  u16*   W2T   = (u16*)  alloc(768ull*3072*2);
  float* qkvb  = (float*)alloc(2304ull*4);

  const float qscale = 0.03608439182435161f * LOG2E;  // D^-0.5 * log2e folded into Wq

  // --- prep ---
  tpose_cast<<<dim3(24,24),dim3(32,8),0,stream>>>(WqkvT,            Wq, 768, 768, qscale);
  tpose_cast<<<dim3(24,24),dim3(32,8),0,stream>>>(WqkvT + 768*768,  Wk, 768, 768, 1.f);
  tpose_cast<<<dim3(24,24),dim3(32,8),0,stream>>>(WqkvT + 1536*768, Wv, 768, 768, 1.f);
  tpose_cast<<<dim3(24,24),dim3(32,8),0,stream>>>(WoT,              Wo, 768, 768, 1.f);
  tpose_cast<<<dim3(96,24),dim3(32,8),0,stream>>>(W1T, W1, 768, 3072, 1.f);
  tpose_cast<<<dim3(24,96),dim3(32,8),0,stream>>>(W2T, W2, 3072, 768, 1.f);
  bias_prep<<<4096,256,0,stream>>>(biasP, sp, ed);
  build_qkvb<<<9,256,0,stream>>>(qkvb, bv);

  // --- layer norms (shared stats) ---
  ln_kernel<<<2048,256,0,stream>>>(x, g1, be1, g2, be2, h1, h2);

  // --- qkv projection ---
  gemm_bt<0><<<dim3(18,64),256,0,stream>>>(h1, WqkvT, qkv, qkvb, nullptr, 8192, 2304, 768);
  vtrans<<<dim3(16,2,192),dim3(32,8),0,stream>>>(qkv, VTg);

  // --- attention ---
  attn_kernel<<<dim3(4,192),256,0,stream>>>(qkv, VTg, biasP, Og);

  // --- output projection + residual x ---
  gemm_bt<1><<<dim3(6,64),256,0,stream>>>(Og, WoT, att, bo, x, 8192, 768, 768);

  // --- FFN ---
  gemm_bt<2><<<dim3(24,64),256,0,stream>>>(h2, W1T, Gg, bf1, nullptr, 8192, 3072, 768);
  gemm_bt<1><<<dim3(6,64),256,0,stream>>>(Gg, W2T, (float*)d_out, bf2, att, 8192, 768, 3072);
}

// Round 3
// 322.318 us; speedup vs baseline: 1.4325x; 1.0906x over previous
//
#include <hip/hip_runtime.h>
#include <math.h>

typedef unsigned short u16;
typedef __bf16 bf16x8 __attribute__((ext_vector_type(8)));
typedef float f32x4 __attribute__((ext_vector_type(4)));

__device__ __forceinline__ u16 f2bf(float f){
  union{float f; unsigned u;} v; v.f = f;
  return (u16)((v.u + 0x7fffu + ((v.u >> 16) & 1u)) >> 16);
}

#define LOG2E 1.4426950408889634f

// ---------------------------------------------------------------------------
// transpose + cast + scale: fp32 [R][C] -> bf16 [C][R] * scale
__global__ void tpose_cast(u16* __restrict__ dst, const float* __restrict__ src,
                           int R, int C, float scale){
  __shared__ float t[32][33];
  int c0 = blockIdx.x * 32, r0 = blockIdx.y * 32;
  int tx = threadIdx.x, ty = threadIdx.y;
  #pragma unroll
  for (int i = 0; i < 4; i++)
    t[ty + i*8][tx] = src[(size_t)(r0 + ty + i*8) * C + c0 + tx];
  __syncthreads();
  #pragma unroll
  for (int i = 0; i < 4; i++)
    dst[(size_t)(c0 + ty + i*8) * R + r0 + tx] = f2bf(t[tx][ty + i*8] * scale);
}

// biasP[b][q][kt][l15][fk] = (sp+ed)[b][q][kt*128 + fk*16 + l15] * log2e - 8*log2e
__global__ void bias_prep(float* __restrict__ dst, const float* __restrict__ sp,
                          const float* __restrict__ ed){
  int t = blockIdx.x * blockDim.x + threadIdx.x;   // 16*512*128
  int row = t >> 7, c0 = (t & 127) * 4;
  size_t base = (size_t)row * 512;
  float4 s = *(const float4*)&sp[base + c0];
  float4 e = *(const float4*)&ed[base + c0];
  const float SH = 8.f * LOG2E;
  int kt = c0 >> 7, cw = c0 & 127, fk = cw >> 4, l0 = cw & 15;
  float* o = dst + base + kt*128 + fk;
  o[(l0+0)*8] = (s.x+e.x)*LOG2E - SH;
  o[(l0+1)*8] = (s.y+e.y)*LOG2E - SH;
  o[(l0+2)*8] = (s.z+e.z)*LOG2E - SH;
  o[(l0+3)*8] = (s.w+e.w)*LOG2E - SH;
}

// qkvb[0:1536)=0, qkvb[1536+i]=bv[i]
__global__ void build_qkvb(float* __restrict__ qkvb, const float* __restrict__ bv){
  int i = blockIdx.x * blockDim.x + threadIdx.x;
  if (i < 2304) qkvb[i] = (i < 1536) ? 0.f : bv[i - 1536];
}

// ---------------------------------------------------------------------------
// LayerNorm: one wave per row, produce h1 (g1,be1) and h2 (g2,be2) in bf16
__global__ __launch_bounds__(256) void ln_kernel(
    const float* __restrict__ x,
    const float* __restrict__ g1, const float* __restrict__ be1,
    const float* __restrict__ g2, const float* __restrict__ be2,
    u16* __restrict__ h1, u16* __restrict__ h2){
  const int lane = threadIdx.x & 63, wave = threadIdx.x >> 6;
  const int row = blockIdx.x * 4 + wave;
  const float4* xr = (const float4*)(x + (size_t)row * 768);
  float4 v[3];
  float sum = 0.f, sq = 0.f;
  #pragma unroll
  for (int c = 0; c < 3; c++){
    v[c] = xr[lane + 64*c];
    sum += v[c].x + v[c].y + v[c].z + v[c].w;
    sq  += v[c].x*v[c].x + v[c].y*v[c].y + v[c].z*v[c].z + v[c].w*v[c].w;
  }
  #pragma unroll
  for (int d = 1; d < 64; d <<= 1){ sum += __shfl_xor(sum, d); sq += __shfl_xor(sq, d); }
  float mu  = sum * (1.f/768.f);
  float var = sq * (1.f/768.f) - mu*mu;
  float rs  = rsqrtf(var + 1e-5f);
  #pragma unroll
  for (int c = 0; c < 3; c++){
    int f4 = lane + 64*c;
    float4 ga = ((const float4*)g1)[f4], ba = ((const float4*)be1)[f4];
    float4 gb = ((const float4*)g2)[f4], bb = ((const float4*)be2)[f4];
    float nx = (v[c].x-mu)*rs, ny = (v[c].y-mu)*rs, nz = (v[c].z-mu)*rs, nw = (v[c].w-mu)*rs;
    ushort4 o1{f2bf(nx*ga.x+ba.x), f2bf(ny*ga.y+ba.y), f2bf(nz*ga.z+ba.z), f2bf(nw*ga.w+ba.w)};
    ushort4 o2{f2bf(nx*gb.x+bb.x), f2bf(ny*gb.y+bb.y), f2bf(nz*gb.z+bb.z), f2bf(nw*gb.w+bb.w)};
    ((ushort4*)(h1 + (size_t)row*768))[f4] = o1;
    ((ushort4*)(h2 + (size_t)row*768))[f4] = o2;
  }
}

// ---------------------------------------------------------------------------
// GEMM (m97 structure): C[M,N] = A[M,K](bf16) @ Bt[N,K](bf16)^T, fp32 accum.
// EPI 0: +bias -> bf16   EPI 1: +bias +resid(f32) -> f32   EPI 2: +bias, gelu -> bf16
template<int EPI>
__global__ __launch_bounds__(256, 2) void gemm_bt(
    const u16* __restrict__ A, const u16* __restrict__ Bt, void* __restrict__ Cout,
    const float* __restrict__ bias, const float* __restrict__ resid,
    int M, int Nn, int K){
  __shared__ __align__(16) u16 As[128*32];
  __shared__ __align__(16) u16 Bs[128*32];
  const int tid = threadIdx.x, lane = tid & 63, wave = tid >> 6;
  const int wm = wave >> 1, wn = wave & 1;
  const int l15 = lane & 15, lg = lane >> 4;
  const int m0 = blockIdx.y * 128, n0 = blockIdx.x * 128;
  f32x4 acc[4][4] = {};
  for (int k0 = 0; k0 < K; k0 += 32){
    #pragma unroll
    for (int i = 0; i < 2; i++){
      int chunk = i*256 + tid;           // 16B chunk index, 512 per tile
      int row = chunk >> 2, seg = chunk & 3;
      __builtin_amdgcn_global_load_lds(
        (const __attribute__((address_space(1))) void*)&A[(size_t)(m0+row)*K + k0 + seg*8],
        (__attribute__((address_space(3))) void*)&As[(size_t)(i*256 + wave*64)*8],
        16, 0, 0);
      __builtin_amdgcn_global_load_lds(
        (const __attribute__((address_space(1))) void*)&Bt[(size_t)(n0+row)*K + k0 + seg*8],
        (__attribute__((address_space(3))) void*)&Bs[(size_t)(i*256 + wave*64)*8],
        16, 0, 0);
    }
    __syncthreads();
    bf16x8 af[4], bfr[4];
    #pragma unroll
    for (int i = 0; i < 4; i++){
      af[i]  = *(const bf16x8*)&As[(wm*64 + i*16 + l15)*32 + lg*8];
      bfr[i] = *(const bf16x8*)&Bs[(wn*64 + i*16 + l15)*32 + lg*8];
    }
    #pragma unroll
    for (int i = 0; i < 4; i++)
      #pragma unroll
      for (int j = 0; j < 4; j++)
        acc[i][j] = __builtin_amdgcn_mfma_f32_16x16x32_bf16(af[i], bfr[j], acc[i][j], 0, 0, 0);
    __syncthreads();
  }
  #pragma unroll
  for (int i = 0; i < 4; i++){
    int row_base = m0 + wm*64 + i*16 + lg*4;
    #pragma unroll
    for (int j = 0; j < 4; j++){
      int col = n0 + wn*64 + j*16 + l15;
      float bb = bias ? bias[col] : 0.f;
      #pragma unroll
      for (int r = 0; r < 4; r++){
        size_t idx = (size_t)(row_base + r) * Nn + col;
        float v = acc[i][j][r] + bb;
        if (EPI == 1){
          v += resid[idx];
          ((float*)Cout)[idx] = v;
        } else if (EPI == 2){
          float u = v + 0.044715f * v * v * v;
          float e = exp2f(-2.3022182f * u);          // exp(-1.5957691*u)
          ((u16*)Cout)[idx] = f2bf(v * __builtin_amdgcn_rcpf(1.f + e));
        } else {
          ((u16*)Cout)[idx] = f2bf(v);
        }
      }
    }
  }
}

// ---------------------------------------------------------------------------
// qkv v-part -> VT [B,H,64,512] via LDS tile transpose.
// Column index is XOR-swizzled within each 128-col tile: chunk ^= (hd&7),
// so attn can stage it linearly into LDS and read bank-conflict-free.
__global__ void vtrans(const u16* __restrict__ qkv, u16* __restrict__ VTg){
  __shared__ u16 t[32][33];
  int bh = blockIdx.z, b = bh / 12, h = bh % 12;
  int n0 = blockIdx.x * 32, hd0 = blockIdx.y * 32;
  int tx = threadIdx.x, ty = threadIdx.y;
  #pragma unroll
  for (int i = 0; i < 4; i++){
    int n = n0 + ty + i*8;
    t[ty + i*8][tx] = qkv[((size_t)(b*512 + n))*2304 + 1536 + h*64 + hd0 + tx];
  }
  __syncthreads();
  #pragma unroll
  for (int i = 0; i < 4; i++){
    int hd = hd0 + ty + i*8;
    int col = n0 + tx;
    int tile = col >> 7, within = col & 127;
    int newcol = (tile << 7) + ((((within >> 3) ^ (hd & 7)) << 3)) + (within & 7);
    VTg[((size_t)bh*64 + hd)*512 + newcol] = t[tx][ty + i*8];
  }
}

// ---------------------------------------------------------------------------
// Attention: block = (q-tile 128) x (b,h); 4 waves, each 32 q-rows.
// K and V tiles are LDS-staged once per block per kt via global_load_lds:
// linear LDS dest + inverse-XOR-swizzled global source + XOR-swizzled ds_read.
__global__ __launch_bounds__(256, 2) void attn_kernel(
    const u16* __restrict__ qkv, const u16* __restrict__ VTg,
    const float* __restrict__ biasP, u16* __restrict__ Og){
  __shared__ __align__(16) u16 Ks[128*64];    // 16 KB, row=n (swizzled chunks)
  __shared__ __align__(16) u16 Vs[64*128];    // 16 KB, row=hd (swizzled chunks)
  __shared__ __align__(16) u16 Pl[4*32*136];  // 34 KB, per-wave private
  const int tid = threadIdx.x, lane = tid & 63, wave = tid >> 6;
  const int l15 = lane & 15, lg = lane >> 4;
  const int bh = blockIdx.y, b = bh / 12, h = bh % 12;
  const int q0 = blockIdx.x * 128 + wave * 32;
  const u16* Qb = qkv + (size_t)b * 512 * 2304 + h * 64;   // row stride 2304
  const u16* Kb = Qb + 768;
  const u16* Vbh = VTg + (size_t)bh * 64 * 512;
  u16* Pw = &Pl[wave * 32 * 136];

  // Q fragments (once; strided global reads, amortized over whole kernel)
  bf16x8 qf[2][2];
  #pragma unroll
  for (int fm = 0; fm < 2; fm++)
    #pragma unroll
    for (int kk = 0; kk < 2; kk++)
      qf[fm][kk] = *(const bf16x8*)&Qb[(size_t)(q0 + fm*16 + l15)*2304 + kk*32 + lg*8];

  f32x4 O[2][4] = {};
  float lrow[2][4] = {};

  for (int kt = 0; kt < 4; kt++){
    const int k0 = kt * 128;
    // bias (pre-permuted): two f32x4 per (fm,r)
    f32x4 bb[2][4][2];
    #pragma unroll
    for (int fm = 0; fm < 2; fm++)
      #pragma unroll
      for (int r = 0; r < 4; r++){
        int qrow = q0 + fm*16 + lg*4 + r;
        const float* bp = biasP + ((size_t)(b*512 + qrow)*4 + kt)*128 + l15*8;
        bb[fm][r][0] = *(const f32x4*)bp;
        bb[fm][r][1] = *(const f32x4*)(bp + 4);
      }
    // stage K tile [128][64] from qkv (inverse-swizzled source, linear dest)
    #pragma unroll
    for (int i = 0; i < 4; i++){
      int chunk = i*256 + tid;              // 1024 chunks of 16B
      int r = chunk >> 3, cc = chunk & 7;
      __builtin_amdgcn_global_load_lds(
        (const __attribute__((address_space(1))) void*)&Kb[(size_t)(b ? 0 : 0) + (size_t)(k0 + r)*2304 + ((cc ^ (r & 7)) << 3)],
        (__attribute__((address_space(3))) void*)&Ks[(size_t)(i*256 + wave*64)*8],
        16, 0, 0);
    }
    // stage V tile [64][128] from pre-swizzled VTg (linear copy)
    #pragma unroll
    for (int i = 0; i < 4; i++){
      int chunk = i*256 + tid;              // 1024 chunks of 16B
      int r = chunk >> 4, cc = chunk & 15;
      __builtin_amdgcn_global_load_lds(
        (const __attribute__((address_space(1))) void*)&Vbh[(size_t)r*512 + k0 + (cc << 3)],
        (__attribute__((address_space(3))) void*)&Vs[(size_t)(i*256 + wave*64)*8],
        16, 0, 0);
    }
    __syncthreads();

    // QK^T from LDS (swizzled reads: 2-way bank alias = free)
    f32x4 S[2][8] = {};
    #pragma unroll
    for (int fk = 0; fk < 8; fk++)
      #pragma unroll
      for (int kk = 0; kk < 2; kk++){
        int row = fk*16 + l15;
        bf16x8 kf = *(const bf16x8*)&Ks[row*64 + (((kk*4 + lg) ^ (l15 & 7)) << 3)];
        S[0][fk] = __builtin_amdgcn_mfma_f32_16x16x32_bf16(qf[0][kk], kf, S[0][fk], 0,0,0);
        S[1][fk] = __builtin_amdgcn_mfma_f32_16x16x32_bf16(qf[1][kk], kf, S[1][fk], 0,0,0);
      }
    // p = exp2(qk' + bias'); row sums (fixed-shift softmax)
    #pragma unroll
    for (int fm = 0; fm < 2; fm++)
      #pragma unroll
      for (int r = 0; r < 4; r++){
        float rs = 0.f;
        #pragma unroll
        for (int fk = 0; fk < 8; fk++){
          float p = exp2f(S[fm][fk][r] + bb[fm][r][fk>>2][fk&3]);
          S[fm][fk][r] = p;
          rs += p;
        }
        rs += __shfl_xor(rs, 1); rs += __shfl_xor(rs, 2);
        rs += __shfl_xor(rs, 4); rs += __shfl_xor(rs, 8);
        lrow[fm][r] += rs;
      }
    // P -> LDS (per-wave private; intra-wave ordering, no extra barrier)
    #pragma unroll
    for (int fm = 0; fm < 2; fm++)
      #pragma unroll
      for (int fk = 0; fk < 8; fk++)
        #pragma unroll
        for (int r = 0; r < 4; r++)
          Pw[(fm*16 + lg*4 + r)*136 + fk*16 + l15] = f2bf(S[fm][fk][r]);
    bf16x8 pf[2][4];
    #pragma unroll
    for (int fm = 0; fm < 2; fm++)
      #pragma unroll
      for (int kk = 0; kk < 4; kk++)
        pf[fm][kk] = *(const bf16x8*)&Pw[(fm*16 + l15)*136 + kk*32 + lg*8];
    // PV from LDS V (swizzled reads)
    #pragma unroll
    for (int fn = 0; fn < 4; fn++)
      #pragma unroll
      for (int kk = 0; kk < 4; kk++){
        int row = fn*16 + l15;
        bf16x8 vf = *(const bf16x8*)&Vs[row*128 + (((kk*4 + lg) ^ (l15 & 7)) << 3)];
        O[0][fn] = __builtin_amdgcn_mfma_f32_16x16x32_bf16(pf[0][kk], vf, O[0][fn], 0,0,0);
        O[1][fn] = __builtin_amdgcn_mfma_f32_16x16x32_bf16(pf[1][kk], vf, O[1][fn], 0,0,0);
      }
    __syncthreads();   // all waves done with Ks/Vs before next stage
  }
  #pragma unroll
  for (int fm = 0; fm < 2; fm++)
    #pragma unroll
    for (int r = 0; r < 4; r++){
      float inv = __builtin_amdgcn_rcpf(lrow[fm][r]);
      int qrow = q0 + fm*16 + lg*4 + r;
      #pragma unroll
      for (int fn = 0; fn < 4; fn++)
        Og[((size_t)b*512 + qrow)*768 + h*64 + fn*16 + l15] = f2bf(O[fm][fn][r] * inv);
    }
}

// ---------------------------------------------------------------------------
extern "C" void kernel_launch(void* const* d_in, const int* in_sizes, int n_in,
                              void* d_out, int out_size, void* d_ws, size_t ws_size,
                              hipStream_t stream){
  const float* x   = (const float*)d_in[0];
  const float* sp  = (const float*)d_in[1];
  const float* ed  = (const float*)d_in[2];
  const float* Wq  = (const float*)d_in[3];
  const float* Wk  = (const float*)d_in[4];
  const float* Wv  = (const float*)d_in[5];
  const float* bv  = (const float*)d_in[6];
  const float* Wo  = (const float*)d_in[7];
  const float* bo  = (const float*)d_in[8];
  const float* g1  = (const float*)d_in[9];
  const float* be1 = (const float*)d_in[10];
  const float* g2  = (const float*)d_in[11];
  const float* be2 = (const float*)d_in[12];
  const float* W1  = (const float*)d_in[13];
  const float* bf1 = (const float*)d_in[14];
  const float* W2  = (const float*)d_in[15];
  const float* bf2 = (const float*)d_in[16];

  char* w = (char*)d_ws;
  size_t off = 0;
  auto alloc = [&](size_t bytes)->void*{ void* p = w + off; off += (bytes + 255) & ~(size_t)255; return p; };
  u16*   Gg    = (u16*)  alloc(8192ull*3072*2);   // FFN1 out; first 37.7MB double as qkv
  u16*   qkv   = Gg;                               // [8192][2304] bf16 (dead before FFN1)
  u16*   VTg   = (u16*)  alloc(8192ull*768*2);
  u16*   h1    = (u16*)  alloc(8192ull*768*2);
  u16*   h2    = (u16*)  alloc(8192ull*768*2);
  u16*   Og    = (u16*)  alloc(8192ull*768*2);
  float* att   = (float*)alloc(8192ull*768*4);
  float* biasP = (float*)alloc(16ull*512*512*4);
  u16*   WqkvT = (u16*)  alloc(2304ull*768*2);
  u16*   WoT   = (u16*)  alloc(768ull*768*2);
  u16*   W1T   = (u16*)  alloc(3072ull*768*2);
  u16*   W2T   = (u16*)  alloc(768ull*3072*2);
  float* qkvb  = (float*)alloc(2304ull*4);

  const float qscale = 0.03608439182435161f * LOG2E;  // D^-0.5 * log2e folded into Wq

  // --- prep ---
  tpose_cast<<<dim3(24,24),dim3(32,8),0,stream>>>(WqkvT,            Wq, 768, 768, qscale);
  tpose_cast<<<dim3(24,24),dim3(32,8),0,stream>>>(WqkvT + 768*768,  Wk, 768, 768, 1.f);
  tpose_cast<<<dim3(24,24),dim3(32,8),0,stream>>>(WqkvT + 1536*768, Wv, 768, 768, 1.f);
  tpose_cast<<<dim3(24,24),dim3(32,8),0,stream>>>(WoT,              Wo, 768, 768, 1.f);
  tpose_cast<<<dim3(96,24),dim3(32,8),0,stream>>>(W1T, W1, 768, 3072, 1.f);
  tpose_cast<<<dim3(24,96),dim3(32,8),0,stream>>>(W2T, W2, 3072, 768, 1.f);
  bias_prep<<<4096,256,0,stream>>>(biasP, sp, ed);
  build_qkvb<<<9,256,0,stream>>>(qkvb, bv);

  // --- layer norms (shared stats) ---
  ln_kernel<<<2048,256,0,stream>>>(x, g1, be1, g2, be2, h1, h2);

  // --- qkv projection ---
  gemm_bt<0><<<dim3(18,64),256,0,stream>>>(h1, WqkvT, qkv, qkvb, nullptr, 8192, 2304, 768);
  vtrans<<<dim3(16,2,192),dim3(32,8),0,stream>>>(qkv, VTg);

  // --- attention ---
  attn_kernel<<<dim3(4,192),256,0,stream>>>(qkv, VTg, biasP, Og);

  // --- output projection + residual x ---
  gemm_bt<1><<<dim3(6,64),256,0,stream>>>(Og, WoT, att, bo, x, 8192, 768, 768);

  // --- FFN ---
  gemm_bt<2><<<dim3(24,64),256,0,stream>>>(h2, W1T, Gg, bf1, nullptr, 8192, 3072, 768);
  gemm_bt<1><<<dim3(6,64),256,0,stream>>>(Gg, W2T, (float*)d_out, bf2, att, 8192, 768, 3072);
}

// Round 4
// 263.562 us; speedup vs baseline: 1.7518x; 1.2229x over previous
//
#include <hip/hip_runtime.h>
#include <math.h>

typedef unsigned short u16;
typedef __bf16 bf16x8 __attribute__((ext_vector_type(8)));
typedef float f32x4 __attribute__((ext_vector_type(4)));

__device__ __forceinline__ u16 f2bf(float f){
  union{float f; unsigned u;} v; v.f = f;
  return (u16)((v.u + 0x7fffu + ((v.u >> 16) & 1u)) >> 16);
}

#define LOG2E 1.4426950408889634f

// ---------------------------------------------------------------------------
// transpose + cast + scale: fp32 [R][C] -> bf16 [C][R] * scale
__global__ void tpose_cast(u16* __restrict__ dst, const float* __restrict__ src,
                           int R, int C, float scale){
  __shared__ float t[32][33];
  int c0 = blockIdx.x * 32, r0 = blockIdx.y * 32;
  int tx = threadIdx.x, ty = threadIdx.y;
  #pragma unroll
  for (int i = 0; i < 4; i++)
    t[ty + i*8][tx] = src[(size_t)(r0 + ty + i*8) * C + c0 + tx];
  __syncthreads();
  #pragma unroll
  for (int i = 0; i < 4; i++)
    dst[(size_t)(c0 + ty + i*8) * R + r0 + tx] = f2bf(t[tx][ty + i*8] * scale);
}

// biasPb[b][q][kt][l15][fk] = bf16( (sp+ed)[b][q][kt*128 + fk*16 + l15] * log2e )
__global__ void bias_prep(u16* __restrict__ dst, const float* __restrict__ sp,
                          const float* __restrict__ ed){
  int t = blockIdx.x * blockDim.x + threadIdx.x;   // 16*512*128
  int row = t >> 7, c0 = (t & 127) * 4;
  size_t base = (size_t)row * 512;
  float4 s = *(const float4*)&sp[base + c0];
  float4 e = *(const float4*)&ed[base + c0];
  int kt = c0 >> 7, cw = c0 & 127, fk = cw >> 4, l0 = cw & 15;
  u16* o = dst + base + kt*128 + fk;
  o[(l0+0)*8] = f2bf((s.x+e.x)*LOG2E);
  o[(l0+1)*8] = f2bf((s.y+e.y)*LOG2E);
  o[(l0+2)*8] = f2bf((s.z+e.z)*LOG2E);
  o[(l0+3)*8] = f2bf((s.w+e.w)*LOG2E);
}

// qkvb[0:1536)=0, qkvb[1536+i]=bv[i]
__global__ void build_qkvb(float* __restrict__ qkvb, const float* __restrict__ bv){
  int i = blockIdx.x * blockDim.x + threadIdx.x;
  if (i < 2304) qkvb[i] = (i < 1536) ? 0.f : bv[i - 1536];
}

// ---------------------------------------------------------------------------
// LayerNorm: one wave per row, produce h1 (g1,be1) and h2 (g2,be2) in bf16
__global__ __launch_bounds__(256) void ln_kernel(
    const float* __restrict__ x,
    const float* __restrict__ g1, const float* __restrict__ be1,
    const float* __restrict__ g2, const float* __restrict__ be2,
    u16* __restrict__ h1, u16* __restrict__ h2){
  const int lane = threadIdx.x & 63, wave = threadIdx.x >> 6;
  const int row = blockIdx.x * 4 + wave;
  const float4* xr = (const float4*)(x + (size_t)row * 768);
  float4 v[3];
  float sum = 0.f, sq = 0.f;
  #pragma unroll
  for (int c = 0; c < 3; c++){
    v[c] = xr[lane + 64*c];
    sum += v[c].x + v[c].y + v[c].z + v[c].w;
    sq  += v[c].x*v[c].x + v[c].y*v[c].y + v[c].z*v[c].z + v[c].w*v[c].w;
  }
  #pragma unroll
  for (int d = 1; d < 64; d <<= 1){ sum += __shfl_xor(sum, d); sq += __shfl_xor(sq, d); }
  float mu  = sum * (1.f/768.f);
  float var = sq * (1.f/768.f) - mu*mu;
  float rs  = rsqrtf(var + 1e-5f);
  #pragma unroll
  for (int c = 0; c < 3; c++){
    int f4 = lane + 64*c;
    float4 ga = ((const float4*)g1)[f4], ba = ((const float4*)be1)[f4];
    float4 gb = ((const float4*)g2)[f4], bb = ((const float4*)be2)[f4];
    float nx = (v[c].x-mu)*rs, ny = (v[c].y-mu)*rs, nz = (v[c].z-mu)*rs, nw = (v[c].w-mu)*rs;
    ushort4 o1{f2bf(nx*ga.x+ba.x), f2bf(ny*ga.y+ba.y), f2bf(nz*ga.z+ba.z), f2bf(nw*ga.w+ba.w)};
    ushort4 o2{f2bf(nx*gb.x+bb.x), f2bf(ny*gb.y+bb.y), f2bf(nz*gb.z+bb.z), f2bf(nw*gb.w+bb.w)};
    ((ushort4*)(h1 + (size_t)row*768))[f4] = o1;
    ((ushort4*)(h2 + (size_t)row*768))[f4] = o2;
  }
}

// ---------------------------------------------------------------------------
// GEMM: C[M,N] = A[M,K](bf16) @ Bt[N,K](bf16)^T, fp32 accum.
// BK=64 (XOR-swizzled LDS via inverse-swizzled global_load_lds source),
// XCD-aware block swizzle (grid must be %8==0).
// EPI 0: +bias -> bf16   EPI 1: +bias +resid(f32) -> f32   EPI 2: +bias, gelu -> bf16
template<int EPI>
__global__ __launch_bounds__(256, 2) void gemm_bt(
    const u16* __restrict__ A, const u16* __restrict__ Bt, void* __restrict__ Cout,
    const float* __restrict__ bias, const float* __restrict__ resid,
    int M, int Nn, int K){
  __shared__ __align__(16) u16 As[128*64];
  __shared__ __align__(16) u16 Bs[128*64];
  const int tid = threadIdx.x, lane = tid & 63, wave = tid >> 6;
  const int wm = wave >> 1, wn = wave & 1;
  const int l15 = lane & 15, lg = lane >> 4;
  // XCD-aware swizzle: consecutive remapped blocks share the A-panel
  const int bid = blockIdx.y * gridDim.x + blockIdx.x;
  const int cpx = (gridDim.x * gridDim.y) >> 3;
  const int swz = (bid & 7) * cpx + (bid >> 3);
  const int m0 = (swz / gridDim.x) * 128, n0 = (swz % gridDim.x) * 128;
  f32x4 acc[4][4] = {};
  for (int k0 = 0; k0 < K; k0 += 64){
    #pragma unroll
    for (int i = 0; i < 4; i++){
      int chunk = i*256 + tid;           // 1024 16B-chunks per tile
      int row = chunk >> 3, seg = (chunk & 7) ^ (row & 7);
      __builtin_amdgcn_global_load_lds(
        (const __attribute__((address_space(1))) void*)&A[(size_t)(m0+row)*K + k0 + seg*8],
        (__attribute__((address_space(3))) void*)&As[(size_t)(i*256 + wave*64)*8],
        16, 0, 0);
      __builtin_amdgcn_global_load_lds(
        (const __attribute__((address_space(1))) void*)&Bt[(size_t)(n0+row)*K + k0 + seg*8],
        (__attribute__((address_space(3))) void*)&Bs[(size_t)(i*256 + wave*64)*8],
        16, 0, 0);
    }
    __syncthreads();
    bf16x8 af[4][2], bfr[4][2];
    #pragma unroll
    for (int i = 0; i < 4; i++){
      int ra = wm*64 + i*16 + l15, rb = wn*64 + i*16 + l15;
      #pragma unroll
      for (int kk = 0; kk < 2; kk++){
        af[i][kk]  = *(const bf16x8*)&As[ra*64 + (((kk*4 + lg) ^ (l15 & 7)) << 3)];
        bfr[i][kk] = *(const bf16x8*)&Bs[rb*64 + (((kk*4 + lg) ^ (l15 & 7)) << 3)];
      }
    }
    #pragma unroll
    for (int kk = 0; kk < 2; kk++)
      #pragma unroll
      for (int i = 0; i < 4; i++)
        #pragma unroll
        for (int j = 0; j < 4; j++)
          acc[i][j] = __builtin_amdgcn_mfma_f32_16x16x32_bf16(af[i][kk], bfr[j][kk], acc[i][j], 0, 0, 0);
    __syncthreads();
  }
  #pragma unroll
  for (int i = 0; i < 4; i++){
    int row_base = m0 + wm*64 + i*16 + lg*4;
    #pragma unroll
    for (int j = 0; j < 4; j++){
      int col = n0 + wn*64 + j*16 + l15;
      float bb = bias ? bias[col] : 0.f;
      #pragma unroll
      for (int r = 0; r < 4; r++){
        size_t idx = (size_t)(row_base + r) * Nn + col;
        float v = acc[i][j][r] + bb;
        if (EPI == 1){
          v += resid[idx];
          ((float*)Cout)[idx] = v;
        } else if (EPI == 2){
          float u = v + 0.044715f * v * v * v;
          float e = exp2f(-2.3022182f * u);          // exp(-1.5957691*u)
          ((u16*)Cout)[idx] = f2bf(v * __builtin_amdgcn_rcpf(1.f + e));
        } else {
          ((u16*)Cout)[idx] = f2bf(v);
        }
      }
    }
  }
}

// ---------------------------------------------------------------------------
// qkv v-part -> VT [B,H,64,512] via LDS tile transpose.
// Column index XOR-swizzled within each 128-col tile (chunk ^= hd&7).
__global__ void vtrans(const u16* __restrict__ qkv, u16* __restrict__ VTg){
  __shared__ u16 t[32][33];
  int bh = blockIdx.z, b = bh / 12, h = bh % 12;
  int n0 = blockIdx.x * 32, hd0 = blockIdx.y * 32;
  int tx = threadIdx.x, ty = threadIdx.y;
  #pragma unroll
  for (int i = 0; i < 4; i++){
    int n = n0 + ty + i*8;
    t[ty + i*8][tx] = qkv[((size_t)(b*512 + n))*2304 + 1536 + h*64 + hd0 + tx];
  }
  __syncthreads();
  #pragma unroll
  for (int i = 0; i < 4; i++){
    int hd = hd0 + ty + i*8;
    int col = n0 + tx;
    int tile = col >> 7, within = col & 127;
    int newcol = (tile << 7) + ((((within >> 3) ^ (hd & 7)) << 3)) + (within & 7);
    VTg[((size_t)bh*64 + hd)*512 + newcol] = t[tx][ty + i*8];
  }
}

// ---------------------------------------------------------------------------
// Attention: block = (q-tile 128) x (b,h); 4 waves, each 32 q-rows.
// K/V LDS-staged per block per kt; bf16 bias; unshifted exp2 softmax.
__global__ __launch_bounds__(256, 2) void attn_kernel(
    const u16* __restrict__ qkv, const u16* __restrict__ VTg,
    const u16* __restrict__ biasPb, u16* __restrict__ Og){
  __shared__ __align__(16) u16 Ks[128*64];
  __shared__ __align__(16) u16 Vs[64*128];
  __shared__ __align__(16) u16 Pl[4*32*136];
  const int tid = threadIdx.x, lane = tid & 63, wave = tid >> 6;
  const int l15 = lane & 15, lg = lane >> 4;
  // XCD swizzle: 4 consecutive remapped blocks share (b,h) K/V
  const int bid = blockIdx.y * 4 + blockIdx.x;           // nwg = 768
  const int swz = (bid & 7) * 96 + (bid >> 3);
  const int bh = swz >> 2, b = bh / 12, h = bh % 12;
  const int q0 = (swz & 3) * 128 + wave * 32;
  const u16* Qb = qkv + (size_t)b * 512 * 2304 + h * 64;   // row stride 2304
  const u16* Kb = Qb + 768;
  const u16* Vbh = VTg + (size_t)bh * 64 * 512;
  u16* Pw = &Pl[wave * 32 * 136];

  bf16x8 qf[2][2];
  #pragma unroll
  for (int fm = 0; fm < 2; fm++)
    #pragma unroll
    for (int kk = 0; kk < 2; kk++)
      qf[fm][kk] = *(const bf16x8*)&Qb[(size_t)(q0 + fm*16 + l15)*2304 + kk*32 + lg*8];

  f32x4 O[2][4] = {};
  float lrow[2][4] = {};

  for (int kt = 0; kt < 4; kt++){
    const int k0 = kt * 128;
    // bias: one bf16x8 per (fm,r)
    bf16x8 bb[2][4];
    #pragma unroll
    for (int fm = 0; fm < 2; fm++)
      #pragma unroll
      for (int r = 0; r < 4; r++){
        int qrow = q0 + fm*16 + lg*4 + r;
        bb[fm][r] = *(const bf16x8*)&biasPb[((size_t)(b*512 + qrow)*4 + kt)*128 + l15*8];
      }
    // stage K tile [128][64] (inverse-swizzled source, linear dest)
    #pragma unroll
    for (int i = 0; i < 4; i++){
      int chunk = i*256 + tid;
      int r = chunk >> 3, cc = chunk & 7;
      __builtin_amdgcn_global_load_lds(
        (const __attribute__((address_space(1))) void*)&Kb[(size_t)(k0 + r)*2304 + ((cc ^ (r & 7)) << 3)],
        (__attribute__((address_space(3))) void*)&Ks[(size_t)(i*256 + wave*64)*8],
        16, 0, 0);
    }
    // stage V tile [64][128] from pre-swizzled VTg (linear copy)
    #pragma unroll
    for (int i = 0; i < 4; i++){
      int chunk = i*256 + tid;
      int r = chunk >> 4, cc = chunk & 15;
      __builtin_amdgcn_global_load_lds(
        (const __attribute__((address_space(1))) void*)&Vbh[(size_t)r*512 + k0 + (cc << 3)],
        (__attribute__((address_space(3))) void*)&Vs[(size_t)(i*256 + wave*64)*8],
        16, 0, 0);
    }
    __syncthreads();

    // QK^T from LDS (swizzled reads)
    f32x4 S[2][8] = {};
    #pragma unroll
    for (int fk = 0; fk < 8; fk++)
      #pragma unroll
      for (int kk = 0; kk < 2; kk++){
        int row = fk*16 + l15;
        bf16x8 kf = *(const bf16x8*)&Ks[row*64 + (((kk*4 + lg) ^ (l15 & 7)) << 3)];
        S[0][fk] = __builtin_amdgcn_mfma_f32_16x16x32_bf16(qf[0][kk], kf, S[0][fk], 0,0,0);
        S[1][fk] = __builtin_amdgcn_mfma_f32_16x16x32_bf16(qf[1][kk], kf, S[1][fk], 0,0,0);
      }
    // p = exp2(qk' + bias'); row sums (no shift needed: args <= ~13, f32 accum)
    #pragma unroll
    for (int fm = 0; fm < 2; fm++)
      #pragma unroll
      for (int r = 0; r < 4; r++){
        float rs = 0.f;
        #pragma unroll
        for (int fk = 0; fk < 8; fk++){
          float p = exp2f(S[fm][fk][r] + (float)bb[fm][r][fk]);
          S[fm][fk][r] = p;
          rs += p;
        }
        rs += __shfl_xor(rs, 1); rs += __shfl_xor(rs, 2);
        rs += __shfl_xor(rs, 4); rs += __shfl_xor(rs, 8);
        lrow[fm][r] += rs;
      }
    // P -> LDS (per-wave private; intra-wave ordering, no extra barrier)
    #pragma unroll
    for (int fm = 0; fm < 2; fm++)
      #pragma unroll
      for (int fk = 0; fk < 8; fk++)
        #pragma unroll
        for (int r = 0; r < 4; r++)
          Pw[(fm*16 + lg*4 + r)*136 + fk*16 + l15] = f2bf(S[fm][fk][r]);
    bf16x8 pf[2][4];
    #pragma unroll
    for (int fm = 0; fm < 2; fm++)
      #pragma unroll
      for (int kk = 0; kk < 4; kk++)
        pf[fm][kk] = *(const bf16x8*)&Pw[(fm*16 + l15)*136 + kk*32 + lg*8];
    // PV from LDS V (swizzled reads)
    #pragma unroll
    for (int fn = 0; fn < 4; fn++)
      #pragma unroll
      for (int kk = 0; kk < 4; kk++){
        int row = fn*16 + l15;
        bf16x8 vf = *(const bf16x8*)&Vs[row*128 + (((kk*4 + lg) ^ (l15 & 7)) << 3)];
        O[0][fn] = __builtin_amdgcn_mfma_f32_16x16x32_bf16(pf[0][kk], vf, O[0][fn], 0,0,0);
        O[1][fn] = __builtin_amdgcn_mfma_f32_16x16x32_bf16(pf[1][kk], vf, O[1][fn], 0,0,0);
      }
    __syncthreads();   // all waves done with Ks/Vs before next stage
  }
  #pragma unroll
  for (int fm = 0; fm < 2; fm++)
    #pragma unroll
    for (int r = 0; r < 4; r++){
      float inv = __builtin_amdgcn_rcpf(lrow[fm][r]);
      int qrow = q0 + fm*16 + lg*4 + r;
      #pragma unroll
      for (int fn = 0; fn < 4; fn++)
        Og[((size_t)b*512 + qrow)*768 + h*64 + fn*16 + l15] = f2bf(O[fm][fn][r] * inv);
    }
}

// ---------------------------------------------------------------------------
extern "C" void kernel_launch(void* const* d_in, const int* in_sizes, int n_in,
                              void* d_out, int out_size, void* d_ws, size_t ws_size,
                              hipStream_t stream){
  const float* x   = (const float*)d_in[0];
  const float* sp  = (const float*)d_in[1];
  const float* ed  = (const float*)d_in[2];
  const float* Wq  = (const float*)d_in[3];
  const float* Wk  = (const float*)d_in[4];
  const float* Wv  = (const float*)d_in[5];
  const float* bv  = (const float*)d_in[6];
  const float* Wo  = (const float*)d_in[7];
  const float* bo  = (const float*)d_in[8];
  const float* g1  = (const float*)d_in[9];
  const float* be1 = (const float*)d_in[10];
  const float* g2  = (const float*)d_in[11];
  const float* be2 = (const float*)d_in[12];
  const float* W1  = (const float*)d_in[13];
  const float* bf1 = (const float*)d_in[14];
  const float* W2  = (const float*)d_in[15];
  const float* bf2 = (const float*)d_in[16];

  char* w = (char*)d_ws;
  size_t off = 0;
  auto alloc = [&](size_t bytes)->void*{ void* p = w + off; off += (bytes + 255) & ~(size_t)255; return p; };
  u16*   Gg    = (u16*)  alloc(8192ull*3072*2);   // FFN1 out; first 37.7MB double as qkv
  u16*   qkv   = Gg;                               // [8192][2304] bf16 (dead before FFN1)
  u16*   VTg   = (u16*)  alloc(8192ull*768*2);
  u16*   h1    = (u16*)  alloc(8192ull*768*2);
  u16*   h2    = (u16*)  alloc(8192ull*768*2);
  u16*   Og    = (u16*)  alloc(8192ull*768*2);
  float* att   = (float*)alloc(8192ull*768*4);
  u16*   biasPb= (u16*)  alloc(16ull*512*512*2);
  u16*   WqkvT = (u16*)  alloc(2304ull*768*2);
  u16*   WoT   = (u16*)  alloc(768ull*768*2);
  u16*   W1T   = (u16*)  alloc(3072ull*768*2);
  u16*   W2T   = (u16*)  alloc(768ull*3072*2);
  float* qkvb  = (float*)alloc(2304ull*4);

  const float qscale = 0.03608439182435161f * LOG2E;  // D^-0.5 * log2e folded into Wq

  // --- prep ---
  tpose_cast<<<dim3(24,24),dim3(32,8),0,stream>>>(WqkvT,            Wq, 768, 768, qscale);
  tpose_cast<<<dim3(24,24),dim3(32,8),0,stream>>>(WqkvT + 768*768,  Wk, 768, 768, 1.f);
  tpose_cast<<<dim3(24,24),dim3(32,8),0,stream>>>(WqkvT + 1536*768, Wv, 768, 768, 1.f);
  tpose_cast<<<dim3(24,24),dim3(32,8),0,stream>>>(WoT,              Wo, 768, 768, 1.f);
  tpose_cast<<<dim3(96,24),dim3(32,8),0,stream>>>(W1T, W1, 768, 3072, 1.f);
  tpose_cast<<<dim3(24,96),dim3(32,8),0,stream>>>(W2T, W2, 3072, 768, 1.f);
  bias_prep<<<4096,256,0,stream>>>(biasPb, sp, ed);
  build_qkvb<<<9,256,0,stream>>>(qkvb, bv);

  // --- layer norms (shared stats) ---
  ln_kernel<<<2048,256,0,stream>>>(x, g1, be1, g2, be2, h1, h2);

  // --- qkv projection ---
  gemm_bt<0><<<dim3(18,64),256,0,stream>>>(h1, WqkvT, qkv, qkvb, nullptr, 8192, 2304, 768);
  vtrans<<<dim3(16,2,192),dim3(32,8),0,stream>>>(qkv, VTg);

  // --- attention ---
  attn_kernel<<<dim3(4,192),256,0,stream>>>(qkv, VTg, biasPb, Og);

  // --- output projection + residual x ---
  gemm_bt<1><<<dim3(6,64),256,0,stream>>>(Og, WoT, att, bo, x, 8192, 768, 768);

  // --- FFN ---
  gemm_bt<2><<<dim3(24,64),256,0,stream>>>(h2, W1T, Gg, bf1, nullptr, 8192, 3072, 768);
  gemm_bt<1><<<dim3(6,64),256,0,stream>>>(Gg, W2T, (float*)d_out, bf2, att, 8192, 768, 3072);
}